// Round 3
// baseline (3302.110 us; speedup 1.0000x reference)
//
#include <hip/hip_runtime.h>
#include <stdint.h>

// ---------------------------------------------------------------------------
// Persistent-kernel LSTM (relu g-gate, h = o*c, no tanh).
// B=128, S=1024, I=256, H=512, O=10.
//
// R10 = R9's proven sync (aggregated per-group counter, TCC atomic poll;
// W=16 capacity-eviction payload freshness) with a shortened per-step
// serial chain:
//  * Direct per-wave fragment loads (R7-proven path) -- the R9 LDS staging
//    (global->drain->LDS->barrier->read) was a BW fix for a latency-bound
//    loop; removed.
//  * Payload loads issued BEFORE the x-part MFMA: vmcnt-domain L2 latency
//    hides under lgkmcnt-domain LDS MFMA work.
//  * Per-wave polling (lane 0 of each wave spins on the group counter via
//    the proven TCC-executed global_atomic_add(0) sc0); B1 barrier deleted.
//    Intra-block wave skew is safe: gates/x_s parities fenced by B3/B4.
//  * Barriers per step: 2 (was 4).
// ---------------------------------------------------------------------------

#define GROUPS 8
#define BC     16
#define S_LEN  1024
#define I_DIM  256
#define H_DIM  512
#define NBLK   512
#define FSTRIDE 16                    // counter stride unit (64 B lines)
#define PAYG   (BC * H_DIM)           // 8192 shorts per group per slot
#define PAYSLOT (GROUPS * PAYG)       // shorts per rotation slot

typedef float f32x4 __attribute__((ext_vector_type(4)));
typedef short s16x8 __attribute__((ext_vector_type(8)));

__device__ __forceinline__ unsigned short f2bf(float f) {
  unsigned u = __float_as_uint(f);
  u += 0x7fffu + ((u >> 16) & 1u);   // RNE
  return (unsigned short)(u >> 16);
}
__device__ __forceinline__ float bf2f(unsigned short h) {
  return __uint_as_float(((unsigned)h) << 16);
}
__device__ __forceinline__ float sigf(float x) { return 1.0f / (1.0f + __expf(-x)); }

// TCC-executed read (atomic add 0, returns old): PROVEN fresh on gfx950.
__device__ __forceinline__ int poll_local(uint64_t a) {
  int v;
  asm volatile("global_atomic_add %0, %1, %2, off sc0\n\ts_waitcnt vmcnt(0)"
               : "=v"(v) : "v"(a), "v"(0) : "memory");
  return v;
}
__device__ __forceinline__ int ld_sc1(uint64_t a) {
  int v;
  asm volatile("global_load_dword %0, %1, off sc1\n\ts_waitcnt vmcnt(0)"
               : "=v"(v) : "v"(a) : "memory");
  return v;
}
__device__ __forceinline__ void st_sc1(uint64_t a, int v) {
  asm volatile("global_store_dword %0, %1, off sc1" :: "v"(a), "v"(v) : "memory");
}
__device__ __forceinline__ void drain_vm() {
  asm volatile("s_waitcnt vmcnt(0)" ::: "memory");
}

__global__ __launch_bounds__(256, 2)
void lstm_persistent(const float* __restrict__ x,
                     const float* __restrict__ Wih,
                     const float* __restrict__ Whh,
                     const float* __restrict__ bih,
                     const float* __restrict__ bhh,
                     const float* __restrict__ fcw,
                     const float* __restrict__ fcb,
                     float* __restrict__ out,
                     int* __restrict__ arrive,           // [1], zeroed
                     int* __restrict__ table,            // [NBLK]
                     int* __restrict__ flags,            // counters, zeroed
                     unsigned short* __restrict__ hpay,  // [W][GROUPS][PAYG]
                     int wmask)
{
  __shared__ __align__(16) unsigned short x_s[2][8][512];  // fragment-order x
  __shared__ __align__(16) float gates[4][BC][18];
  __shared__ int tbl[NBLK];
  __shared__ unsigned long long seen[GROUPS][4];
  __shared__ int s_grp, s_slot, s_abort;

  const int tid  = threadIdx.x;
  const int wave = tid >> 6;        // gate section 0..3 (i,f,g,o)
  const int lane = tid & 63;
  const int q    = lane >> 4;
  const int l15  = lane & 15;
  const int bid  = blockIdx.x;

  // ---- rendezvous: publish (xcd, cu-key), wait for all, elect workers ----
  const int xcd = __builtin_amdgcn_s_getreg((31u << 11) | 20) & 7;     // XCC_ID
  const int cuk = __builtin_amdgcn_s_getreg((7u << 11) | (8u << 6) | 4) & 0xff; // HW_ID[15:8]
  if (tid == 0) {
    st_sc1((uint64_t)&table[bid], xcd | (cuk << 3));
    drain_vm();
    atomicAdd(arrive, 1);
    int spins = 0;
    while (atomicAdd(arrive, 0) < NBLK && spins < (1 << 22)) {
      __builtin_amdgcn_s_sleep(8);
      ++spins;
    }
  }
  if (tid < 32) *(unsigned long long*)&seen[tid >> 2][tid & 3] = 0ull;
  __syncthreads();
  tbl[tid]       = ld_sc1((uint64_t)&table[tid]);
  tbl[tid + 256] = ld_sc1((uint64_t)&table[tid + 256]);
  __syncthreads();
  if (tid == 0) {
    int cnt[8]    = {0, 0, 0, 0, 0, 0, 0, 0};
    int wcount[8] = {0, 0, 0, 0, 0, 0, 0, 0};
    int my_rank = 0, my_w = -1;
    for (int j = 0; j < NBLK; ++j) {
      const int e  = tbl[j];
      const int xx = e & 7;
      const int ky = (e >> 3) & 0xff;
      const unsigned long long bit = 1ull << (ky & 63);
      const bool first = !(seen[xx][ky >> 6] & bit);
      if (first) seen[xx][ky >> 6] |= bit;
      int w = -1;
      if (first && wcount[xx] < 32) w = wcount[xx]++;
      if (j == bid) { my_rank = cnt[xx]; my_w = w; }
      cnt[xx]++;
    }
    int slot = my_w;
    if (wcount[xcd] != 32)                 // CU-key aliasing: safe fallback
      slot = (my_rank < 32) ? my_rank : -1;
    s_grp = (slot >= 0) ? xcd : -1;
    s_slot = slot;
    s_abort = 0;
  }
  __syncthreads();
  const int g    = s_grp;
  const int slot = s_slot;
  if (g < 0) return;                       // surplus block exits

  // ---- persistent weight fragments (B-frag: lane holds B[k=q*8+j][n=l15]) ----
  const int gcol = wave * H_DIM + slot * 16 + l15;   // gate row 0..2047
  s16x8 bhh_f[16];
#pragma unroll
  for (int kb = 0; kb < 16; ++kb) {
    const float* src = Whh + (size_t)gcol * H_DIM + kb * 32 + q * 8;
    s16x8 v;
#pragma unroll
    for (int i = 0; i < 8; ++i) v[i] = (short)f2bf(src[i]);
    bhh_f[kb] = v;
  }
  s16x8 bih_f[8];
#pragma unroll
  for (int kb = 0; kb < 8; ++kb) {
    const float* src = Wih + (size_t)gcol * I_DIM + kb * 32 + q * 8;
    s16x8 v;
#pragma unroll
    for (int i = 0; i < 8; ++i) v[i] = (short)f2bf(src[i]);
    bih_f[kb] = v;
  }
  const float bias_v = bih[gcol] + bhh[gcol];

  // ---- x staging geometry: thread covers row m0, cols kc0*16..+15 ----
  const int m0  = tid & 15;
  const int kc0 = tid >> 4;
  const int xkb   = kc0 >> 1;
  const int laneA = m0 + 32 * (kc0 & 1);
  const int laneB = laneA + 16;
  const float* const xrow = x + (size_t)(g * BC + m0) * S_LEN * I_DIM + kc0 * 16;

  // ---- preload: x[0] -> LDS parity 0; x[1] -> regs xN ----
  {
    float xt[16];
    *(float4*)&xt[0]  = ((const float4*)xrow)[0];
    *(float4*)&xt[4]  = ((const float4*)xrow)[1];
    *(float4*)&xt[8]  = ((const float4*)xrow)[2];
    *(float4*)&xt[12] = ((const float4*)xrow)[3];
    s16x8 v0, v1;
#pragma unroll
    for (int i = 0; i < 8; ++i) { v0[i] = (short)f2bf(xt[i]); v1[i] = (short)f2bf(xt[8 + i]); }
    *(s16x8*)&x_s[0][xkb][laneA * 8] = v0;
    *(s16x8*)&x_s[0][xkb][laneB * 8] = v1;
  }
  float xN[16];
  {
    const float* src = xrow + (size_t)1 * I_DIM;
    *(float4*)&xN[0]  = ((const float4*)src)[0];
    *(float4*)&xN[4]  = ((const float4*)src)[1];
    *(float4*)&xN[8]  = ((const float4*)src)[2];
    *(float4*)&xN[12] = ((const float4*)src)[3];
  }
  __syncthreads();

  // per-group aggregated step counter (own 64-B line, zeroed at launch)
  int* const gcnt = flags + (size_t)g * 32 * FSTRIDE;

  // producer store coordinates (fragment-order payload)
  const int erow  = wave * 4 + q;
  const int kcol  = slot * 16 + l15;
  const int sidx  = (kcol >> 5) * 512 + (erow + 16 * ((kcol >> 3) & 3)) * 8 + (kcol & 7);

  int p = 0;
  float c_reg = 0.0f;

  for (int t = 0; t < S_LEN; ++t) {
    // ---- 1) issue x[t+2] loads (consumed next step: HBM latency hidden) ----
    float xF[16];
    if (t + 2 < S_LEN) {
      const float* src = xrow + (size_t)(t + 2) * I_DIM;
      *(float4*)&xF[0]  = ((const float4*)src)[0];
      *(float4*)&xF[4]  = ((const float4*)src)[1];
      *(float4*)&xF[8]  = ((const float4*)src)[2];
      *(float4*)&xF[12] = ((const float4*)src)[3];
    }

    // ---- 2) stash xN (= x[t+1], loaded a full step ago) into other parity ----
    //        (off critical path: runs while producers finish step t)
    if (t + 1 < S_LEN) {
      s16x8 v0, v1;
#pragma unroll
      for (int i = 0; i < 8; ++i) { v0[i] = (short)f2bf(xN[i]); v1[i] = (short)f2bf(xN[8 + i]); }
      *(s16x8*)&x_s[p ^ 1][xkb][laneA * 8] = v0;
      *(s16x8*)&x_s[p ^ 1][xkb][laneB * 8] = v1;
    }

    // ---- 3) per-wave poll: all 32 peers posted step t (TCC atomic read) ----
    if (t > 0) {
      if (lane == 0 && !s_abort) {
        const int need = 32 * t;
        int rounds = 0;
        while (poll_local((uint64_t)gcnt) < need) {
          if (++rounds > (1 << 16)) { s_abort = 1; break; }
        }
      }
      // wave reconverges here; no block barrier needed (gates/x_s fenced
      // by B3/B4 below)
    }

    // ---- 4) issue payload fragment loads (plain; W=16 eviction freshness);
    //         L2 latency hides under the x-part MFMA below ----
    s16x8 afr[16];
    if (t > 0) {
      const unsigned short* pb =
          hpay + (size_t)((t & wmask) * GROUPS + g) * PAYG + lane * 8;
#pragma unroll
      for (int kb = 0; kb < 16; ++kb)
        afr[kb] = *(const s16x8*)(pb + kb * 512);
    }

    // ---- 5) x-part of gates from LDS (lgkm domain; overlaps afr loads) ----
    f32x4 acc = {bias_v, bias_v, bias_v, bias_v};
#pragma unroll
    for (int kb = 0; kb < 8; ++kb) {
      s16x8 a = *(const s16x8*)&x_s[p][kb][lane * 8];
      acc = __builtin_amdgcn_mfma_f32_16x16x32_bf16(a, bih_f[kb], acc, 0, 0, 0);
    }

    // ---- 6) h-part MFMA ----
    if (t > 0) {
      f32x4 h0 = {0.f, 0.f, 0.f, 0.f}, h1 = {0.f, 0.f, 0.f, 0.f};
#pragma unroll
      for (int kb = 0; kb < 16; kb += 2) {
        h0 = __builtin_amdgcn_mfma_f32_16x16x32_bf16(afr[kb],     bhh_f[kb],     h0, 0, 0, 0);
        h1 = __builtin_amdgcn_mfma_f32_16x16x32_bf16(afr[kb + 1], bhh_f[kb + 1], h1, 0, 0, 0);
      }
      acc += h0 + h1;
    }

    // ---- 7) publish gate section (C/D: col=l15, row=q*4+r) ----
#pragma unroll
    for (int r = 0; r < 4; ++r) gates[wave][q * 4 + r][l15] = acc[r];
    __syncthreads();                               // B3: gates ready

    // ---- 8) elementwise; lane owns (row=erow, col=kcol); store h_{t+1} ----
    {
      float yi = gates[0][erow][l15];
      float yf = gates[1][erow][l15];
      float yg = gates[2][erow][l15];
      float yo = gates[3][erow][l15];
      float ig = sigf(yi), fg = sigf(yf), gg = fmaxf(yg, 0.0f), og = sigf(yo);
      c_reg = fg * c_reg + ig * gg;
      float h = og * c_reg;
      hpay[(size_t)(((t + 1) & wmask) * GROUPS + g) * PAYG + sidx] = f2bf(h);
    }

    // ---- 9) drain stores (all threads), barrier, then ONE counter post ----
    drain_vm();
    __syncthreads();                               // B4: block fully drained
    if (tid == 0) atomicAdd(gcnt, 1);

    // ---- 10) advance pipeline ----
#pragma unroll
    for (int i = 0; i < 16; ++i) xN[i] = xF[i];
    p ^= 1;
  }

  // ---- final FC by slot-0 block; h_S in slot (S_LEN & wmask) == 0 ----
  if (slot == 0) {
    if (tid == 0 && !s_abort) {
      int rounds = 0;
      while (poll_local((uint64_t)gcnt) < 32 * S_LEN) {
        if (++rounds > (1 << 16)) break;
      }
    }
    __syncthreads();
    unsigned short* hfc = &x_s[0][0][0];           // reuse as [16][512]
    {
      const unsigned short* pb = hpay + (size_t)g * PAYG + (size_t)tid * 32;
      s16x8 cc[4];
      cc[0] = ((const s16x8*)pb)[0];
      cc[1] = ((const s16x8*)pb)[1];
      cc[2] = ((const s16x8*)pb)[2];
      cc[3] = ((const s16x8*)pb)[3];
      const int kb = tid >> 4;
      const int L0 = (tid & 15) * 4;
#pragma unroll
      for (int i = 0; i < 4; ++i) {
        const int L = L0 + i;
        const int m = L & 15, qq = L >> 4;
        *(s16x8*)&hfc[m * 512 + kb * 32 + qq * 8] = cc[i];
      }
    }
    __syncthreads();

    if (tid < BC * 10) {
      const int row = tid / 10, o = tid - row * 10;
      const float* wr = fcw + (size_t)o * H_DIM;
      float sum = fcb[o];
      for (int k = 0; k < H_DIM; k += 8) {
#pragma unroll
        for (int j = 0; j < 8; ++j)
          sum += bf2f(hfc[row * 512 + k + j]) * wr[k + j];
      }
      out[(g * BC + row) * 10 + o] = sum;
    }
  }
}

extern "C" void kernel_launch(void* const* d_in, const int* in_sizes, int n_in,
                              void* d_out, int out_size, void* d_ws, size_t ws_size,
                              hipStream_t stream) {
  (void)in_sizes; (void)n_in; (void)out_size;
  const float* x   = (const float*)d_in[0];
  const float* Wih = (const float*)d_in[1];
  const float* Whh = (const float*)d_in[2];
  const float* bih = (const float*)d_in[3];
  const float* bhh = (const float*)d_in[4];
  const float* fcw = (const float*)d_in[5];
  const float* fcb = (const float*)d_in[6];

  int* arrive = (int*)d_ws;                          // @0
  int* table  = (int*)((char*)d_ws + 4096);          // @4K, 512 ints
  int* flags  = (int*)((char*)d_ws + 8192);          // @8K, per-group counters
  unsigned short* hpay = (unsigned short*)((char*)d_ws + 32768);

  // rotation depth W: power of two, 2..16 (16 => ~512 KB vL1 turnover per
  // address reuse -- the PROVEN plain-load freshness mechanism)
  size_t avail = ws_size > 32768 ? ws_size - 32768 : 0;
  int W = 2;
  while (W < 16 && (size_t)(W * 2) * (PAYSLOT * 2) <= avail) W <<= 1;

  // zero arrive + table + counter region (counters MUST start at 0;
  // re-zeroed every launch -> graph-replay safe)
  hipMemsetAsync(d_ws, 0, 32768, stream);

  hipLaunchKernelGGL(lstm_persistent, dim3(NBLK), dim3(256), 0, stream,
                     x, Wih, Whh, bih, bhh, fcw, fcb, (float*)d_out,
                     arrive, table, flags, hpay, W - 1);
}

// Round 4
// 2271.499 us; speedup vs baseline: 1.4537x; 1.4537x over previous
//
#include <hip/hip_runtime.h>
#include <stdint.h>

// ---------------------------------------------------------------------------
// Persistent-kernel LSTM (relu g-gate, h = o*c, no tanh).
// B=128, S=1024, I=256, H=512, O=10.
//
// R11 = R9 byte-identical EXCEPT the group sync counter is spread across
// 4 sub-counter lines (256 B apart) to cut same-line TCC atomic
// serialization (R10 post-mortem: poll latency scales with per-line RMW
// queue depth; R9 had 32 pollers + 32 posters on ONE line).
//  * Producers post to line (slot & 3): 8 posts/line/step, target 8t.
//  * Consumer polls with lanes 0..3 in ONE predicated vector atomic
//    (4 addresses -> 4 TCC channels in parallel).
//  * Correctness: first block to post t+1 observed all 4 lines >= 8t with
//    all counts <= t  =>  all peers exactly t (same induction as R9).
//  * Everything else unchanged: LDS staging, W=16 capacity-eviction
//    freshness, B1/B3/B4 barriers, x double-buffer pipeline.
// ---------------------------------------------------------------------------

#define GROUPS 8
#define BC     16
#define S_LEN  1024
#define I_DIM  256
#define H_DIM  512
#define NBLK   512
#define FSTRIDE 16                    // flag stride unit (64 B)
#define SUBSTRIDE 64                  // sub-counter stride in ints (256 B)
#define PAYG   (BC * H_DIM)           // 8192 shorts per group per slot
#define PAYSLOT (GROUPS * PAYG)       // shorts per rotation slot

typedef float f32x4 __attribute__((ext_vector_type(4)));
typedef short s16x8 __attribute__((ext_vector_type(8)));

__device__ __forceinline__ unsigned short f2bf(float f) {
  unsigned u = __float_as_uint(f);
  u += 0x7fffu + ((u >> 16) & 1u);   // RNE
  return (unsigned short)(u >> 16);
}
__device__ __forceinline__ float bf2f(unsigned short h) {
  return __uint_as_float(((unsigned)h) << 16);
}
__device__ __forceinline__ float sigf(float x) { return 1.0f / (1.0f + __expf(-x)); }

// TCC-executed read (atomic add 0, returns old): PROVEN fresh on gfx950.
__device__ __forceinline__ int poll_local(uint64_t a) {
  int v;
  asm volatile("global_atomic_add %0, %1, %2, off sc0\n\ts_waitcnt vmcnt(0)"
               : "=v"(v) : "v"(a), "v"(0) : "memory");
  return v;
}
__device__ __forceinline__ int ld_sc1(uint64_t a) {
  int v;
  asm volatile("global_load_dword %0, %1, off sc1\n\ts_waitcnt vmcnt(0)"
               : "=v"(v) : "v"(a) : "memory");
  return v;
}
__device__ __forceinline__ void st_sc1(uint64_t a, int v) {
  asm volatile("global_store_dword %0, %1, off sc1" :: "v"(a), "v"(v) : "memory");
}
__device__ __forceinline__ void drain_vm() {
  asm volatile("s_waitcnt vmcnt(0)" ::: "memory");
}

__global__ __launch_bounds__(256, 2)
void lstm_persistent(const float* __restrict__ x,
                     const float* __restrict__ Wih,
                     const float* __restrict__ Whh,
                     const float* __restrict__ bih,
                     const float* __restrict__ bhh,
                     const float* __restrict__ fcw,
                     const float* __restrict__ fcb,
                     float* __restrict__ out,
                     int* __restrict__ arrive,           // [1], zeroed
                     int* __restrict__ table,            // [NBLK]
                     int* __restrict__ flags,            // counters, zeroed
                     unsigned short* __restrict__ hpay,  // [W][GROUPS][PAYG]
                     int wmask)
{
  __shared__ __align__(16) unsigned short x_s[2][8][512];  // fragment-order x
  __shared__ __align__(16) unsigned short h_stage[8192];   // one group-slot of h
  __shared__ __align__(16) float gates[4][BC][18];
  __shared__ int tbl[NBLK];
  __shared__ unsigned long long seen[GROUPS][4];
  __shared__ int s_grp, s_slot, s_abort;

  const int tid  = threadIdx.x;
  const int wave = tid >> 6;        // gate section 0..3 (i,f,g,o)
  const int lane = tid & 63;
  const int q    = lane >> 4;
  const int l15  = lane & 15;
  const int bid  = blockIdx.x;

  // ---- rendezvous: publish (xcd, cu-key), wait for all, elect workers ----
  const int xcd = __builtin_amdgcn_s_getreg((31u << 11) | 20) & 7;     // XCC_ID
  const int cuk = __builtin_amdgcn_s_getreg((7u << 11) | (8u << 6) | 4) & 0xff; // HW_ID[15:8]
  if (tid == 0) {
    st_sc1((uint64_t)&table[bid], xcd | (cuk << 3));
    drain_vm();
    atomicAdd(arrive, 1);
    int spins = 0;
    while (atomicAdd(arrive, 0) < NBLK && spins < (1 << 22)) {
      __builtin_amdgcn_s_sleep(8);
      ++spins;
    }
  }
  if (tid < 32) *(unsigned long long*)&seen[tid >> 2][tid & 3] = 0ull;
  __syncthreads();
  tbl[tid]       = ld_sc1((uint64_t)&table[tid]);
  tbl[tid + 256] = ld_sc1((uint64_t)&table[tid + 256]);
  __syncthreads();
  if (tid == 0) {
    int cnt[8]    = {0, 0, 0, 0, 0, 0, 0, 0};
    int wcount[8] = {0, 0, 0, 0, 0, 0, 0, 0};
    int my_rank = 0, my_w = -1;
    for (int j = 0; j < NBLK; ++j) {
      const int e  = tbl[j];
      const int xx = e & 7;
      const int ky = (e >> 3) & 0xff;
      const unsigned long long bit = 1ull << (ky & 63);
      const bool first = !(seen[xx][ky >> 6] & bit);
      if (first) seen[xx][ky >> 6] |= bit;
      int w = -1;
      if (first && wcount[xx] < 32) w = wcount[xx]++;
      if (j == bid) { my_rank = cnt[xx]; my_w = w; }
      cnt[xx]++;
    }
    int slot = my_w;
    if (wcount[xcd] != 32)                 // CU-key aliasing: safe fallback
      slot = (my_rank < 32) ? my_rank : -1;
    s_grp = (slot >= 0) ? xcd : -1;
    s_slot = slot;
    s_abort = 0;
  }
  __syncthreads();
  const int g    = s_grp;
  const int slot = s_slot;
  if (g < 0) return;                       // surplus block exits

  // ---- persistent weight fragments (B-frag: lane holds B[k=q*8+j][n=l15]) ----
  const int gcol = wave * H_DIM + slot * 16 + l15;   // gate row 0..2047
  s16x8 bhh_f[16];
#pragma unroll
  for (int kb = 0; kb < 16; ++kb) {
    const float* src = Whh + (size_t)gcol * H_DIM + kb * 32 + q * 8;
    s16x8 v;
#pragma unroll
    for (int i = 0; i < 8; ++i) v[i] = (short)f2bf(src[i]);
    bhh_f[kb] = v;
  }
  s16x8 bih_f[8];
#pragma unroll
  for (int kb = 0; kb < 8; ++kb) {
    const float* src = Wih + (size_t)gcol * I_DIM + kb * 32 + q * 8;
    s16x8 v;
#pragma unroll
    for (int i = 0; i < 8; ++i) v[i] = (short)f2bf(src[i]);
    bih_f[kb] = v;
  }
  const float bias_v = bih[gcol] + bhh[gcol];

  // ---- x staging geometry: thread covers row m0, cols kc0*16..+15 ----
  const int m0  = tid & 15;
  const int kc0 = tid >> 4;
  const int xkb   = kc0 >> 1;
  const int laneA = m0 + 32 * (kc0 & 1);
  const int laneB = laneA + 16;
  const float* const xrow = x + (size_t)(g * BC + m0) * S_LEN * I_DIM + kc0 * 16;

  // ---- preload: x[0] -> LDS parity 0; x[1] -> regs xN ----
  {
    float xt[16];
    *(float4*)&xt[0]  = ((const float4*)xrow)[0];
    *(float4*)&xt[4]  = ((const float4*)xrow)[1];
    *(float4*)&xt[8]  = ((const float4*)xrow)[2];
    *(float4*)&xt[12] = ((const float4*)xrow)[3];
    s16x8 v0, v1;
#pragma unroll
    for (int i = 0; i < 8; ++i) { v0[i] = (short)f2bf(xt[i]); v1[i] = (short)f2bf(xt[8 + i]); }
    *(s16x8*)&x_s[0][xkb][laneA * 8] = v0;
    *(s16x8*)&x_s[0][xkb][laneB * 8] = v1;
  }
  float xN[16];
  {
    const float* src = xrow + (size_t)1 * I_DIM;
    *(float4*)&xN[0]  = ((const float4*)src)[0];
    *(float4*)&xN[4]  = ((const float4*)src)[1];
    *(float4*)&xN[8]  = ((const float4*)src)[2];
    *(float4*)&xN[12] = ((const float4*)src)[3];
  }
  __syncthreads();

  // per-group sub-counters: 4 lines, 256 B apart, zeroed at launch
  int* const gcnt = flags + (size_t)g * 32 * FSTRIDE;

  // producer store coordinates (fragment-order payload)
  const int erow  = wave * 4 + q;
  const int kcol  = slot * 16 + l15;
  const int sidx  = (kcol >> 5) * 512 + (erow + 16 * ((kcol >> 3) & 3)) * 8 + (kcol & 7);

  int p = 0;
  float c_reg = 0.0f;

  for (int t = 0; t < S_LEN; ++t) {
    // ---- 1) issue x[t+2] loads (consumed next step: HBM latency hidden) ----
    float xF[16];
    if (t + 2 < S_LEN) {
      const float* src = xrow + (size_t)(t + 2) * I_DIM;
      *(float4*)&xF[0]  = ((const float4*)src)[0];
      *(float4*)&xF[4]  = ((const float4*)src)[1];
      *(float4*)&xF[8]  = ((const float4*)src)[2];
      *(float4*)&xF[12] = ((const float4*)src)[3];
    }

    // ---- 2) x-part of gates from LDS ----
    f32x4 acc = {bias_v, bias_v, bias_v, bias_v};
#pragma unroll
    for (int kb = 0; kb < 8; ++kb) {
      s16x8 a = *(const s16x8*)&x_s[p][kb][lane * 8];
      acc = __builtin_amdgcn_mfma_f32_16x16x32_bf16(a, bih_f[kb], acc, 0, 0, 0);
    }

    // ---- 3) stash xN (= x[t+1], loaded a full step ago) into other parity ----
    if (t + 1 < S_LEN) {
      s16x8 v0, v1;
#pragma unroll
      for (int i = 0; i < 8; ++i) { v0[i] = (short)f2bf(xN[i]); v1[i] = (short)f2bf(xN[8 + i]); }
      *(s16x8*)&x_s[p ^ 1][xkb][laneA * 8] = v0;
      *(s16x8*)&x_s[p ^ 1][xkb][laneB * 8] = v1;
    }

    if (t > 0) {
      // ---- 4) 4-lane poll of 4 sub-counter lines (one vector atomic) ----
      if (tid < 4 && !s_abort) {
        const uint64_t a = (uint64_t)(gcnt + (size_t)tid * SUBSTRIDE);
        const int need = 8 * t;
        int rounds = 0;
        for (;;) {
          int v = poll_local(a);
          if (__all(v >= need)) break;     // exec = lanes 0..3 only
          if (++rounds > (1 << 16)) { if (tid == 0) s_abort = 1; break; }
        }
      }
      __syncthreads();                             // B1: h_t published
      // ---- 4b) stage payload -> LDS once (plain loads; W=16 eviction) ----
      {
        const unsigned short* pb =
            hpay + (size_t)((t & wmask) * GROUPS + g) * PAYG + (size_t)tid * 8;
        s16x8 c0 = *(const s16x8*)(pb);
        s16x8 c1 = *(const s16x8*)(pb + 2048);
        s16x8 c2 = *(const s16x8*)(pb + 4096);
        s16x8 c3 = *(const s16x8*)(pb + 6144);
        *(s16x8*)&h_stage[tid * 8]        = c0;
        *(s16x8*)&h_stage[tid * 8 + 2048] = c1;
        *(s16x8*)&h_stage[tid * 8 + 4096] = c2;
        *(s16x8*)&h_stage[tid * 8 + 6144] = c3;
      }
      __syncthreads();                             // B2: h_stage ready
      f32x4 h0 = {0.f, 0.f, 0.f, 0.f}, h1 = {0.f, 0.f, 0.f, 0.f};
#pragma unroll
      for (int kb = 0; kb < 16; kb += 2) {
        const s16x8 a0 = *(const s16x8*)&h_stage[(kb    ) * 512 + lane * 8];
        const s16x8 a1 = *(const s16x8*)&h_stage[(kb + 1) * 512 + lane * 8];
        h0 = __builtin_amdgcn_mfma_f32_16x16x32_bf16(a0, bhh_f[kb],     h0, 0, 0, 0);
        h1 = __builtin_amdgcn_mfma_f32_16x16x32_bf16(a1, bhh_f[kb + 1], h1, 0, 0, 0);
      }
      acc += h0 + h1;
    }

    // ---- 5) publish gate section (C/D: col=l15, row=q*4+r) ----
#pragma unroll
    for (int r = 0; r < 4; ++r) gates[wave][q * 4 + r][l15] = acc[r];
    __syncthreads();                               // B3: gates ready

    // ---- 6) elementwise; lane owns (row=erow, col=kcol); store h_{t+1} ----
    {
      float yi = gates[0][erow][l15];
      float yf = gates[1][erow][l15];
      float yg = gates[2][erow][l15];
      float yo = gates[3][erow][l15];
      float ig = sigf(yi), fg = sigf(yf), gg = fmaxf(yg, 0.0f), og = sigf(yo);
      c_reg = fg * c_reg + ig * gg;
      float h = og * c_reg;
      hpay[(size_t)(((t + 1) & wmask) * GROUPS + g) * PAYG + sidx] = f2bf(h);
    }

    // ---- 7) drain stores (all threads), barrier, then ONE counter post ----
    drain_vm();
    __syncthreads();                               // B4: block fully drained
    if (tid == 0) atomicAdd(gcnt + (size_t)(slot & 3) * SUBSTRIDE, 1);

    // ---- 8) advance pipeline ----
#pragma unroll
    for (int i = 0; i < 16; ++i) xN[i] = xF[i];
    p ^= 1;
  }

  // ---- final FC by slot-0 block; h_S in slot (S_LEN & wmask) == 0 ----
  if (slot == 0) {
    if (tid < 4 && !s_abort) {
      const uint64_t a = (uint64_t)(gcnt + (size_t)tid * SUBSTRIDE);
      const int need = 8 * S_LEN;
      int rounds = 0;
      for (;;) {
        int v = poll_local(a);
        if (__all(v >= need)) break;
        if (++rounds > (1 << 16)) break;
      }
    }
    __syncthreads();
    unsigned short* hfc = &x_s[0][0][0];           // reuse as [16][512]
    {
      const unsigned short* pb = hpay + (size_t)g * PAYG + (size_t)tid * 32;
      s16x8 cc[4];
      cc[0] = ((const s16x8*)pb)[0];
      cc[1] = ((const s16x8*)pb)[1];
      cc[2] = ((const s16x8*)pb)[2];
      cc[3] = ((const s16x8*)pb)[3];
      const int kb = tid >> 4;
      const int L0 = (tid & 15) * 4;
#pragma unroll
      for (int i = 0; i < 4; ++i) {
        const int L = L0 + i;
        const int m = L & 15, qq = L >> 4;
        *(s16x8*)&hfc[m * 512 + kb * 32 + qq * 8] = cc[i];
      }
    }
    __syncthreads();

    if (tid < BC * 10) {
      const int row = tid / 10, o = tid - row * 10;
      const float* wr = fcw + (size_t)o * H_DIM;
      float sum = fcb[o];
      for (int k = 0; k < H_DIM; k += 8) {
#pragma unroll
        for (int j = 0; j < 8; ++j)
          sum += bf2f(hfc[row * 512 + k + j]) * wr[k + j];
      }
      out[(g * BC + row) * 10 + o] = sum;
    }
  }
}

extern "C" void kernel_launch(void* const* d_in, const int* in_sizes, int n_in,
                              void* d_out, int out_size, void* d_ws, size_t ws_size,
                              hipStream_t stream) {
  (void)in_sizes; (void)n_in; (void)out_size;
  const float* x   = (const float*)d_in[0];
  const float* Wih = (const float*)d_in[1];
  const float* Whh = (const float*)d_in[2];
  const float* bih = (const float*)d_in[3];
  const float* bhh = (const float*)d_in[4];
  const float* fcw = (const float*)d_in[5];
  const float* fcb = (const float*)d_in[6];

  int* arrive = (int*)d_ws;                          // @0
  int* table  = (int*)((char*)d_ws + 4096);          // @4K, 512 ints
  int* flags  = (int*)((char*)d_ws + 8192);          // @8K, per-group sub-counters
  unsigned short* hpay = (unsigned short*)((char*)d_ws + 32768);

  // rotation depth W: power of two, 2..16 (16 => ~512 KB vL1 turnover per
  // address reuse -- the PROVEN plain-load freshness mechanism)
  size_t avail = ws_size > 32768 ? ws_size - 32768 : 0;
  int W = 2;
  while (W < 16 && (size_t)(W * 2) * (PAYSLOT * 2) <= avail) W <<= 1;

  // zero arrive + table + counter region (counters MUST start at 0;
  // re-zeroed every launch -> graph-replay safe)
  hipMemsetAsync(d_ws, 0, 32768, stream);

  hipLaunchKernelGGL(lstm_persistent, dim3(NBLK), dim3(256), 0, stream,
                     x, Wih, Whh, bih, bhh, fcw, fcb, (float*)d_out,
                     arrive, table, flags, hpay, W - 1);
}